// Round 15
// baseline (661.505 us; speedup 1.0000x reference)
//
#include <hip/hip_runtime.h>
#include <hip/hip_cooperative_groups.h>
#include <math.h>

#define NN 100000
#define NE 3200000
#define NR 90
#define NB 391          // buckets of 256 nodes (dst>>8)
#define CH 4096         // edges per chunk in pass1
#define NCHUNK 782      // ceil(NE/CH)
#define CAP 12288       // padded per-bucket capacity (mean 8192, +45 sigma)

typedef unsigned int u32;
typedef unsigned short u16;

namespace cg = cooperative_groups;

__device__ inline u32 pack2(float a, float b) {       // bf16(a) lo16, bf16(b) hi16 (RNE)
    u32 ua = __float_as_uint(a); ua += 0x7FFFu + ((ua >> 16) & 1u);
    u32 ub = __float_as_uint(b); ub += 0x7FFFu + ((ub >> 16) & 1u);
    return (ua >> 16) | (ub & 0xFFFF0000u);
}
__device__ inline float unlo(u32 w) { return __uint_as_float(w << 16); }
__device__ inline float unhi(u32 w) { return __uint_as_float(w & 0xFFFF0000u); }

// LDS arena (words): pass1 uses 1685 + 4096 (lrecs) + 2048 (lbid as u16[4096]) = 7829
//                    pass2 uses 768 + 5888 (cnt32) = 6656
#define SMEMW 7840

__global__ __launch_bounds__(512) void fused_kernel(
        const int* __restrict__ src, const int* __restrict__ dst,
        const int* __restrict__ et,
        const float* __restrict__ x,
        const float* __restrict__ w1, const float* __restrict__ root1, const float* __restrict__ b1,
        const float* __restrict__ w2, const float* __restrict__ root2, const float* __restrict__ b2,
        const float* __restrict__ w3, const float* __restrict__ root3, const float* __restrict__ b3,
        float* __restrict__ out,
        u32* ccursor, uint2* off2, u32* tmp, u32* recs,
        uint2* xb, uint4* h1b, u32* h2b) {
    cg::grid_group grid = cg::this_grid();
    __shared__ u32 smem[SMEMW];
    int tid = threadIdx.x;

    // ---------------- phase 0: zero bucket cursors ----------------
    if (blockIdx.x == 0)
        for (int i = tid; i < NB; i += 512) ccursor[i] = 0;
    __threadfence();
    grid.sync();

    // ---------------- phase 1: coarse partition into padded bucket windows ----------------
    {
        u32* cntA  = smem;              // [391]
        u32* lcur  = smem + 391;        // [391]
        u32* delta = smem + 782;        // [391]
        u32* scanS = smem + 1173;       // [512]
        u32* lrecs = smem + 1685;       // [4096]
        u16* lbid  = (u16*)(smem + 5781); // [4096]
        for (int chunk = blockIdx.x; chunk < NCHUNK; chunk += gridDim.x) {
            int c0 = chunk * CH;
            int c1 = c0 + CH; if (c1 > NE) c1 = NE;
            int nloc = c1 - c0;
            if (tid < NB) cntA[tid] = 0;
            __syncthreads();
            for (int e = c0 + tid; e < c1; e += 512)
                atomicAdd(&cntA[(u32)dst[e] >> 8], 1u);
            __syncthreads();
            scanS[tid] = (tid < NB) ? cntA[tid] : 0u;
            __syncthreads();
#pragma unroll
            for (int ofs = 1; ofs < 512; ofs <<= 1) {
                u32 v = (tid >= ofs) ? scanS[tid - ofs] : 0u;
                __syncthreads();
                scanS[tid] += v;
                __syncthreads();
            }
            if (tid < NB) {
                u32 excl = (tid == 0) ? 0u : scanS[tid - 1];
                lcur[tid] = excl;
                u32 c = cntA[tid];
                delta[tid] = c ? ((u32)tid * CAP + atomicAdd(&ccursor[tid], c) - excl) : 0u;
            }
            __syncthreads();
            for (int e = c0 + tid; e < c1; e += 512) {
                u32 d = (u32)dst[e];
                u32 b = d >> 8;
                u32 pos = atomicAdd(&lcur[b], 1u);
                lrecs[pos] = ((d & 255u) << 24) | ((u32)src[e] << 7) | (u32)et[e];
                lbid[pos] = (u16)b;
            }
            __syncthreads();
            for (int k = tid; k < nloc; k += 512)
                tmp[delta[lbid[k]] + k] = lrecs[k];
            __syncthreads();
        }
    }
    __threadfence();
    grid.sync();

    // ---------------- phase 2: per-bucket fine sort; off2, recs(cnt<<24|src<<7|et), xb ----------------
    {
        u32* dh    = smem;              // [256]
        u32* lc2   = smem + 256;        // [256]
        u32* sh    = smem + 512;        // [256]
        u32* cnt32 = smem + 768;        // [5888]
        for (int b = blockIdx.x; b < NB; b += gridDim.x) {
            u32 r0 = (u32)b * CAP;
            u32 r1 = r0 + ccursor[b];
            if (tid < 256) dh[tid] = 0;
            for (int i = tid; i < 256 * 23; i += 512) cnt32[i] = 0;
            __syncthreads();
            for (u32 k = r0 + tid; k < r1; k += 512)
                atomicAdd(&dh[tmp[k] >> 24], 1u);
            __syncthreads();
            if (tid < 256) sh[tid] = dh[tid];
            __syncthreads();
#pragma unroll
            for (int ofs = 1; ofs < 256; ofs <<= 1) {
                u32 v = (tid >= ofs && tid < 256) ? sh[tid - ofs] : 0u;
                __syncthreads();
                if (tid < 256) sh[tid] += v;
                __syncthreads();
            }
            int n = b * 256 + tid;
            if (tid < 256) {
                u32 excl = (tid == 0) ? 0u : sh[tid - 1];
                if (n < NN) off2[n] = make_uint2(r0 + excl, r0 + sh[tid]);
                lc2[tid] = excl;
            }
            __syncthreads();
            for (u32 k = r0 + tid; k < r1; k += 512) {
                u32 v = tmp[k];
                u32 ln = v >> 24;
                u32 rec = v & 0xFFFFFFu;
                u32 rel = v & 127u;
                u32 pos = atomicAdd(&lc2[ln], 1u);
                recs[r0 + pos] = rec;
                atomicAdd(&cnt32[ln * 23 + (rel >> 2)], 1u << ((rel & 3u) * 8u));
            }
            __syncthreads();
            if (tid < 256 && n < NN) {
                u32 start = (tid == 0) ? 0u : sh[tid - 1];
                u32 end = sh[tid];
                for (u32 j = start; j < end; j++) {
                    u32 rel = recs[r0 + j] & 127u;
                    u32 c = (cnt32[tid * 23 + (rel >> 2)] >> ((rel & 3u) * 8u)) & 255u;
                    recs[r0 + j] |= c << 24;
                }
                float4 xv = *(const float4*)(x + (size_t)n * 4);
                xb[n] = make_uint2(pack2(xv.x, xv.y), pack2(xv.z, xv.w));
            }
            __syncthreads();
        }
    }
    __threadfence();
    grid.sync();

    // ---------------- phase 3: layer 1 (mean + root + bias + relu) ----------------
    for (u32 gid = blockIdx.x * 512u + tid; gid < NN * 8u; gid += gridDim.x * 512u) {
        u32 n = gid >> 3, r = gid & 7;
        float acc[8];
#pragma unroll
        for (int j = 0; j < 8; j++) acc[j] = 0.0f;
        uint2 o = off2[n];
        for (u32 k = o.x + r; k < o.y; k += 8) {
            u32 rec = recs[k];
            u32 t = rec & 127u, s = (rec >> 7) & 0x1FFFFu;
            float norm = 1.0f / (float)(rec >> 24);
            uint2 xw = xb[s];
            float x0 = unlo(xw.x) * norm, x1 = unhi(xw.x) * norm;
            float x2 = unlo(xw.y) * norm, x3 = unhi(xw.y) * norm;
            const float* w = w1 + (size_t)t * 16;   // [2][2][4]
#pragma unroll
            for (int o2 = 0; o2 < 4; o2++) {
                acc[o2]     += x0 * w[o2]     + x1 * w[4 + o2];
                acc[4 + o2] += x2 * w[8 + o2] + x3 * w[12 + o2];
            }
        }
#pragma unroll
        for (int j = 0; j < 8; j++) {
            acc[j] += __shfl_xor(acc[j], 1);
            acc[j] += __shfl_xor(acc[j], 2);
            acc[j] += __shfl_xor(acc[j], 4);
        }
        if (r == 0) {
            float4 xn = *(const float4*)(x + (size_t)n * 4);
            float h[8];
#pragma unroll
            for (int j = 0; j < 8; j++) {
                float v = acc[j] + b1[j] + xn.x * root1[j] + xn.y * root1[8 + j]
                        + xn.z * root1[16 + j] + xn.w * root1[24 + j];
                h[j] = fmaxf(v, 0.0f);
            }
            h1b[n] = make_uint4(pack2(h[0], h[1]), pack2(h[2], h[3]),
                                pack2(h[4], h[5]), pack2(h[6], h[7]));
        }
    }
    __threadfence();
    grid.sync();

    // ---------------- phase 4: layer 2 (add + root + bias + relu) ----------------
    for (u32 gid = blockIdx.x * 512u + tid; gid < NN * 8u; gid += gridDim.x * 512u) {
        u32 n = gid >> 3, r = gid & 7;
        float acc[12];
#pragma unroll
        for (int j = 0; j < 12; j++) acc[j] = 0.0f;
        uint2 o = off2[n];
        for (u32 k = o.x + r; k < o.y; k += 8) {
            u32 rec = recs[k];
            u32 t = rec & 127u, s = (rec >> 7) & 0x1FFFFu;
            uint4 hw = h1b[s];
            float a0 = unlo(hw.x), a1 = unhi(hw.x), a2 = unlo(hw.y), a3 = unhi(hw.y);
            float a4 = unlo(hw.z), a5 = unhi(hw.z), a6 = unlo(hw.w), a7 = unhi(hw.w);
            const float* w = w2 + (size_t)t * 24;   // [4][2][3]
#pragma unroll
            for (int o2 = 0; o2 < 3; o2++) {
                acc[o2]     += a0 * w[o2]      + a1 * w[3 + o2];
                acc[3 + o2] += a2 * w[6 + o2]  + a3 * w[9 + o2];
                acc[6 + o2] += a4 * w[12 + o2] + a5 * w[15 + o2];
                acc[9 + o2] += a6 * w[18 + o2] + a7 * w[21 + o2];
            }
        }
#pragma unroll
        for (int j = 0; j < 12; j++) {
            acc[j] += __shfl_xor(acc[j], 1);
            acc[j] += __shfl_xor(acc[j], 2);
            acc[j] += __shfl_xor(acc[j], 4);
        }
        if (r == 0) {
            uint4 hn = h1b[n];
            float hv[8] = { unlo(hn.x), unhi(hn.x), unlo(hn.y), unhi(hn.y),
                            unlo(hn.z), unhi(hn.z), unlo(hn.w), unhi(hn.w) };
            float h[12];
#pragma unroll
            for (int j = 0; j < 12; j++) {
                float v = acc[j] + b2[j];
#pragma unroll
                for (int i = 0; i < 8; i++) v += hv[i] * root2[i * 12 + j];
                h[j] = fmaxf(v, 0.0f);
            }
            u32* hb = h2b + (size_t)n * 8;         // 32B stride, 24B used
            *(uint4*)hb = make_uint4(pack2(h[0], h[1]), pack2(h[2], h[3]),
                                     pack2(h[4], h[5]), pack2(h[6], h[7]));
            *(uint2*)(hb + 4) = make_uint2(pack2(h[8], h[9]), pack2(h[10], h[11]));
        }
    }
    __threadfence();
    grid.sync();

    // ---------------- phase 5: layer 3 (mean + root + bias + log_softmax) ----------------
    for (u32 gid = blockIdx.x * 512u + tid; gid < NN * 8u; gid += gridDim.x * 512u) {
        u32 n = gid >> 3, r = gid & 7;
        float acc[4] = {0.0f, 0.0f, 0.0f, 0.0f};
        uint2 o = off2[n];
        for (u32 k = o.x + r; k < o.y; k += 8) {
            u32 rec = recs[k];
            u32 t = rec & 127u, s = (rec >> 7) & 0x1FFFFu;
            float norm = 1.0f / (float)(rec >> 24);
            const u32* hb = h2b + (size_t)s * 8;
            uint4 q = *(const uint4*)hb;
            uint2 p = *(const uint2*)(hb + 4);
            float hsv[12] = { unlo(q.x), unhi(q.x), unlo(q.y), unhi(q.y),
                              unlo(q.z), unhi(q.z), unlo(q.w), unhi(q.w),
                              unlo(p.x), unhi(p.x), unlo(p.y), unhi(p.y) };
            const float* w = w3 + (size_t)t * 24;   // [2][6][2]
            float m0 = 0.0f, m1 = 0.0f, m2 = 0.0f, m3 = 0.0f;
#pragma unroll
            for (int i = 0; i < 6; i++) {
                m0 += hsv[i] * w[i * 2];          m1 += hsv[i] * w[i * 2 + 1];
                m2 += hsv[6 + i] * w[12 + i * 2]; m3 += hsv[6 + i] * w[12 + i * 2 + 1];
            }
            acc[0] += m0 * norm; acc[1] += m1 * norm;
            acc[2] += m2 * norm; acc[3] += m3 * norm;
        }
#pragma unroll
        for (int j = 0; j < 4; j++) {
            acc[j] += __shfl_xor(acc[j], 1);
            acc[j] += __shfl_xor(acc[j], 2);
            acc[j] += __shfl_xor(acc[j], 4);
        }
        if (r == 0) {
            const u32* hbn = h2b + (size_t)n * 8;
            uint4 qn = *(const uint4*)hbn; uint2 pn = *(const uint2*)(hbn + 4);
            float hv[12] = { unlo(qn.x), unhi(qn.x), unlo(qn.y), unhi(qn.y),
                             unlo(qn.z), unhi(qn.z), unlo(qn.w), unhi(qn.w),
                             unlo(pn.x), unhi(pn.x), unlo(pn.y), unhi(pn.y) };
            float t4[4];
#pragma unroll
            for (int j = 0; j < 4; j++) {
                float v = acc[j] + b3[j];
#pragma unroll
                for (int i = 0; i < 12; i++) v += hv[i] * root3[i * 4 + j];
                t4[j] = v;
            }
            float m = fmaxf(fmaxf(t4[0], t4[1]), fmaxf(t4[2], t4[3]));
            float s = 0.0f;
#pragma unroll
            for (int j = 0; j < 4; j++) s += __expf(t4[j] - m);
            float lse = m + __logf(s);
            *(float4*)(out + (size_t)n * 4) =
                make_float4(t4[0] - lse, t4[1] - lse, t4[2] - lse, t4[3] - lse);
        }
    }
}

extern "C" void kernel_launch(void* const* d_in, const int* in_sizes, int n_in,
                              void* d_out, int out_size, void* d_ws, size_t ws_size,
                              hipStream_t stream) {
    const float* x     = (const float*)d_in[0];
    const int*   ei    = (const int*)d_in[1];   // [2, E]
    const int*   etype = (const int*)d_in[2];
    const float* w1    = (const float*)d_in[3];
    const float* root1 = (const float*)d_in[4];
    const float* b1    = (const float*)d_in[5];
    const float* w2    = (const float*)d_in[6];
    const float* root2 = (const float*)d_in[7];
    const float* b2    = (const float*)d_in[8];
    const float* w3    = (const float*)d_in[9];
    const float* root3 = (const float*)d_in[10];
    const float* b3    = (const float*)d_in[11];
    float* out = (float*)d_out;

    const int* src = ei;
    const int* dst = ei + NE;

    // workspace layout (bytes) — identical to round 14:
    //   ccursor : [NB]      u32   @ 0
    //   off2    : [NN]      uint2 @ 1,600
    //   tmp     : [NB*CAP]  u32   @ 801,664
    //   recs    : [NB*CAP]  u32   @ 20,020,224
    //   xb      : [NN]      8B    @ 39,238,656
    //   h1b     : [NN]      16B   @ 40,038,656
    //   h2b     : [NN]      32B   @ 41,638,656   -> total 44,838,656
    char* ws = (char*)d_ws;
    u32*   ccursor = (u32*)ws;
    uint2* off2    = (uint2*)(ws + 1600);
    u32*   tmp     = (u32*)(ws + 801664);
    u32*   recs    = (u32*)(ws + 20020224);
    uint2* xb      = (uint2*)(ws + 39238656);
    uint4* h1b     = (uint4*)(ws + 40038656);
    u32*   h2b     = (u32*)(ws + 41638656);

    // grid sized to exact co-residency (deterministic each call; no static state)
    int maxBlocksPerCU = 0;
    hipOccupancyMaxActiveBlocksPerMultiprocessor(&maxBlocksPerCU, fused_kernel, 512, 0);
    if (maxBlocksPerCU < 1) maxBlocksPerCU = 1;
    int grid = maxBlocksPerCU * 256;            // 256 CUs on MI355X
    if (grid > 1024) grid = 1024;

    void* args[] = {
        (void*)&src, (void*)&dst, (void*)&etype,
        (void*)&x,
        (void*)&w1, (void*)&root1, (void*)&b1,
        (void*)&w2, (void*)&root2, (void*)&b2,
        (void*)&w3, (void*)&root3, (void*)&b3,
        (void*)&out,
        (void*)&ccursor, (void*)&off2, (void*)&tmp, (void*)&recs,
        (void*)&xb, (void*)&h1b, (void*)&h2b
    };
    hipLaunchCooperativeKernel(fused_kernel, dim3(grid), dim3(512), args, 0, stream);
}

// Round 16
// 267.575 us; speedup vs baseline: 2.4722x; 2.4722x over previous
//
#include <hip/hip_runtime.h>
#include <math.h>

#define NN 100000
#define NE 3200000
#define NR 90
#define NB 391          // buckets of 256 nodes (dst>>8)
#define CH 4096         // edges per block in pass1
#define NCHUNK 782      // ceil(NE/CH)
#define CAP 12288       // padded per-bucket capacity (mean 8192, +45 sigma)

typedef unsigned int u32;
typedef unsigned short u16;

__device__ inline u32 pack2(float a, float b) {       // bf16(a) lo16, bf16(b) hi16 (RNE)
    u32 ua = __float_as_uint(a); ua += 0x7FFFu + ((ua >> 16) & 1u);
    u32 ub = __float_as_uint(b); ub += 0x7FFFu + ((ub >> 16) & 1u);
    return (ua >> 16) | (ub & 0xFFFF0000u);
}
__device__ inline float unlo(u32 w) { return __uint_as_float(w << 16); }
__device__ inline float unhi(u32 w) { return __uint_as_float(w & 0xFFFF0000u); }

// ---------------- pass 1: direct padded-bucket partition (no pre-count) ----------------
// tmp entry: (dst&255)<<24 | src<<7 | et ; bucket b's window is tmp[b*CAP ..]
__global__ __launch_bounds__(512) void pass1_kernel(const int* __restrict__ src,
                                                    const int* __restrict__ dst,
                                                    const int* __restrict__ et,
                                                    u32* __restrict__ ccursor,
                                                    u32* __restrict__ tmp) {
    __shared__ u32 cntA[NB];
    __shared__ u32 lcur[NB];
    __shared__ u32 delta[NB];
    __shared__ u32 scanS[512];
    __shared__ u32 lrecs[CH];
    __shared__ u16 lbid[CH];
    int tid = threadIdx.x;
    int c0 = blockIdx.x * CH;
    int c1 = c0 + CH; if (c1 > NE) c1 = NE;
    int nloc = c1 - c0;

    if (tid < NB) cntA[tid] = 0;
    __syncthreads();

    for (int e = c0 + tid; e < c1; e += 512)
        atomicAdd(&cntA[(u32)dst[e] >> 8], 1u);
    __syncthreads();

    scanS[tid] = (tid < NB) ? cntA[tid] : 0u;
    __syncthreads();
#pragma unroll
    for (int ofs = 1; ofs < 512; ofs <<= 1) {
        u32 v = (tid >= ofs) ? scanS[tid - ofs] : 0u;
        __syncthreads();
        scanS[tid] += v;
        __syncthreads();
    }
    if (tid < NB) {
        u32 excl = (tid == 0) ? 0u : scanS[tid - 1];
        lcur[tid] = excl;
        u32 c = cntA[tid];
        delta[tid] = c ? ((u32)tid * CAP + atomicAdd(&ccursor[tid], c) - excl) : 0u;
    }
    __syncthreads();

    for (int e = c0 + tid; e < c1; e += 512) {
        u32 d = (u32)dst[e];
        u32 b = d >> 8;
        u32 pos = atomicAdd(&lcur[b], 1u);
        lrecs[pos] = ((d & 255u) << 24) | ((u32)src[e] << 7) | (u32)et[e];
        lbid[pos] = (u16)b;
    }
    __syncthreads();

    for (int k = tid; k < nloc; k += 512)
        tmp[delta[lbid[k]] + k] = lrecs[k];
}

// ---------------- pass 2 + layer 1 fused ----------------
// per-bucket fine sort -> off2=(start,end), recs(cnt<<24|src<<7|et);
// then layer1 (mean-aggr + root + bias + relu) for this bucket's 256 nodes,
// reading the just-written (L2-hot) recs and gathering fp32 x directly.
__global__ __launch_bounds__(512) void pass2_kernel(const u32* __restrict__ tmp,
                                                    const u32* __restrict__ ccursor,
                                                    uint2* __restrict__ off2,
                                                    u32* __restrict__ recs,
                                                    const float* __restrict__ x,
                                                    const float* __restrict__ w1,
                                                    const float* __restrict__ root1,
                                                    const float* __restrict__ b1,
                                                    uint4* __restrict__ h1b) {
    __shared__ u32 dh[256];          // per-node degree
    __shared__ u32 lc2[256];         // per-node cursor (relative)
    __shared__ u32 cnt32[256 * 23];  // per-(node,rel) u8 counts packed 4/word
    __shared__ u32 sh[256];          // inclusive scan (survives all phases)
    int tid = threadIdx.x;
    int b = blockIdx.x;
    u32 r0 = (u32)b * CAP;
    u32 r1 = r0 + ccursor[b];        // cursor's final value == bucket edge count

    if (tid < 256) dh[tid] = 0;
    for (int i = tid; i < 256 * 23; i += 512) cnt32[i] = 0;
    __syncthreads();

    // A: per-node degrees
    for (u32 k = r0 + tid; k < r1; k += 512)
        atomicAdd(&dh[tmp[k] >> 24], 1u);
    __syncthreads();

    // B: inclusive scan of dh (256 entries)
    if (tid < 256) sh[tid] = dh[tid];
    __syncthreads();
#pragma unroll
    for (int ofs = 1; ofs < 256; ofs <<= 1) {
        u32 v = (tid >= ofs && tid < 256) ? sh[tid - ofs] : 0u;
        __syncthreads();
        if (tid < 256) sh[tid] += v;
        __syncthreads();
    }
    int n = b * 256 + tid;
    if (tid < 256) {
        u32 excl = (tid == 0) ? 0u : sh[tid - 1];
        if (n < NN) off2[n] = make_uint2(r0 + excl, r0 + sh[tid]);
        lc2[tid] = excl;
    }
    __syncthreads();

    // C: fine scatter into this bucket's recs window + per-(node,rel) counts
    for (u32 k = r0 + tid; k < r1; k += 512) {
        u32 v = tmp[k];
        u32 ln = v >> 24;
        u32 rec = v & 0xFFFFFFu;
        u32 rel = v & 127u;
        u32 pos = atomicAdd(&lc2[ln], 1u);
        recs[r0 + pos] = rec;
        atomicAdd(&cnt32[ln * 23 + (rel >> 2)], 1u << ((rel & 3u) * 8u));
    }
    __syncthreads();

    // D: embed per-(node,rel) count into top byte of each rec
    if (tid < 256 && n < NN) {
        u32 start = (tid == 0) ? 0u : sh[tid - 1];
        u32 end = sh[tid];
        for (u32 j = start; j < end; j++) {
            u32 rel = recs[r0 + j] & 127u;
            u32 c = (cnt32[tid * 23 + (rel >> 2)] >> ((rel & 3u) * 8u)) & 255u;
            recs[r0 + j] |= c << 24;
        }
    }
    __syncthreads();

    // E: layer 1 for this bucket's 256 nodes — 8 lanes/node, 4 sweeps of 64 nodes
#pragma unroll
    for (int g = 0; g < 4; g++) {
        int ln = g * 64 + (tid >> 3);          // 0..255
        int r = tid & 7;
        int nn = b * 256 + ln;
        float acc[8];
#pragma unroll
        for (int j = 0; j < 8; j++) acc[j] = 0.0f;
        if (nn < NN) {
            u32 k0 = r0 + ((ln == 0) ? 0u : sh[ln - 1]);
            u32 k1 = r0 + sh[ln];
            for (u32 k = k0 + r; k < k1; k += 8) {
                u32 rec = recs[k];
                u32 t = rec & 127u, s = (rec >> 7) & 0x1FFFFu;
                float norm = 1.0f / (float)(rec >> 24);
                float4 xv = *(const float4*)(x + (size_t)s * 4);
                float x0 = xv.x * norm, x1 = xv.y * norm;
                float x2 = xv.z * norm, x3 = xv.w * norm;
                const float* w = w1 + (size_t)t * 16;   // [2][2][4]
#pragma unroll
                for (int o = 0; o < 4; o++) {
                    acc[o]     += x0 * w[o]     + x1 * w[4 + o];
                    acc[4 + o] += x2 * w[8 + o] + x3 * w[12 + o];
                }
            }
        }
#pragma unroll
        for (int j = 0; j < 8; j++) {
            acc[j] += __shfl_xor(acc[j], 1);
            acc[j] += __shfl_xor(acc[j], 2);
            acc[j] += __shfl_xor(acc[j], 4);
        }
        if (r == 0 && nn < NN) {
            float4 xn = *(const float4*)(x + (size_t)nn * 4);
            float h[8];
#pragma unroll
            for (int j = 0; j < 8; j++) {
                float v = acc[j] + b1[j] + xn.x * root1[j] + xn.y * root1[8 + j]
                        + xn.z * root1[16 + j] + xn.w * root1[24 + j];
                h[j] = fmaxf(v, 0.0f);
            }
            h1b[nn] = make_uint4(pack2(h[0], h[1]), pack2(h[2], h[3]),
                                 pack2(h[4], h[5]), pack2(h[6], h[7]));
        }
    }
}

// ======== layers 2/3: 8 lanes/node, plain loads, bf16 tables (round-14 best, unchanged) ========

// ---------------- layer 2: add-aggr + root + bias + relu ----------------
__global__ __launch_bounds__(256) void layer2_kernel(
        const uint2* __restrict__ off2, const u32* __restrict__ recs,
        const uint4* __restrict__ h1b,
        const float* __restrict__ w2, const float* __restrict__ root2,
        const float* __restrict__ b2, u32* __restrict__ h2b) {
    int gid = blockIdx.x * 256 + threadIdx.x;
    int n = gid >> 3, r = gid & 7;
    if (n >= NN) return;
    float acc[12];
#pragma unroll
    for (int j = 0; j < 12; j++) acc[j] = 0.0f;

    uint2 o = off2[n];
    u32 k0 = o.x, k1 = o.y;
    for (u32 k = k0 + r; k < k1; k += 8) {
        u32 rec = recs[k];
        u32 t = rec & 127u, s = (rec >> 7) & 0x1FFFFu;
        uint4 hw = h1b[s];
        float a0 = unlo(hw.x), a1 = unhi(hw.x), a2 = unlo(hw.y), a3 = unhi(hw.y);
        float a4 = unlo(hw.z), a5 = unhi(hw.z), a6 = unlo(hw.w), a7 = unhi(hw.w);
        const float* w = w2 + (size_t)t * 24;   // [4][2][3]
#pragma unroll
        for (int o2 = 0; o2 < 3; o2++) {
            acc[o2]     += a0 * w[o2]      + a1 * w[3 + o2];
            acc[3 + o2] += a2 * w[6 + o2]  + a3 * w[9 + o2];
            acc[6 + o2] += a4 * w[12 + o2] + a5 * w[15 + o2];
            acc[9 + o2] += a6 * w[18 + o2] + a7 * w[21 + o2];
        }
    }
#pragma unroll
    for (int j = 0; j < 12; j++) {
        acc[j] += __shfl_xor(acc[j], 1);
        acc[j] += __shfl_xor(acc[j], 2);
        acc[j] += __shfl_xor(acc[j], 4);
    }
    if (r != 0) return;
    uint4 hn = h1b[n];
    float hv[8] = { unlo(hn.x), unhi(hn.x), unlo(hn.y), unhi(hn.y),
                    unlo(hn.z), unhi(hn.z), unlo(hn.w), unhi(hn.w) };
    float h[12];
#pragma unroll
    for (int j = 0; j < 12; j++) {
        float v = acc[j] + b2[j];
#pragma unroll
        for (int i = 0; i < 8; i++) v += hv[i] * root2[i * 12 + j];
        h[j] = fmaxf(v, 0.0f);
    }
    u32* hb = h2b + (size_t)n * 8;             // 32B stride, 24B used
    *(uint4*)hb = make_uint4(pack2(h[0], h[1]), pack2(h[2], h[3]),
                             pack2(h[4], h[5]), pack2(h[6], h[7]));
    *(uint2*)(hb + 4) = make_uint2(pack2(h[8], h[9]), pack2(h[10], h[11]));
}

// ---------------- layer 3: mean-aggr + root + bias + log_softmax ----------------
__global__ __launch_bounds__(256) void layer3_kernel(
        const uint2* __restrict__ off2, const u32* __restrict__ recs,
        const u32* __restrict__ h2b,
        const float* __restrict__ w3, const float* __restrict__ root3,
        const float* __restrict__ b3, float* __restrict__ out) {
    int gid = blockIdx.x * 256 + threadIdx.x;
    int n = gid >> 3, r = gid & 7;
    if (n >= NN) return;
    float acc[4] = {0.0f, 0.0f, 0.0f, 0.0f};
    uint2 o = off2[n];
    u32 k0 = o.x, k1 = o.y;
    for (u32 k = k0 + r; k < k1; k += 8) {
        u32 rec = recs[k];
        u32 t = rec & 127u, s = (rec >> 7) & 0x1FFFFu;
        float norm = 1.0f / (float)(rec >> 24);
        const u32* hb = h2b + (size_t)s * 8;
        uint4 q = *(const uint4*)hb;
        uint2 p = *(const uint2*)(hb + 4);
        float hsv[12] = { unlo(q.x), unhi(q.x), unlo(q.y), unhi(q.y),
                          unlo(q.z), unhi(q.z), unlo(q.w), unhi(q.w),
                          unlo(p.x), unhi(p.x), unlo(p.y), unhi(p.y) };
        const float* w = w3 + (size_t)t * 24;   // [2][6][2]
        float m0 = 0.0f, m1 = 0.0f, m2 = 0.0f, m3 = 0.0f;
#pragma unroll
        for (int i = 0; i < 6; i++) {
            m0 += hsv[i] * w[i * 2];          m1 += hsv[i] * w[i * 2 + 1];
            m2 += hsv[6 + i] * w[12 + i * 2]; m3 += hsv[6 + i] * w[12 + i * 2 + 1];
        }
        acc[0] += m0 * norm; acc[1] += m1 * norm;
        acc[2] += m2 * norm; acc[3] += m3 * norm;
    }
#pragma unroll
    for (int j = 0; j < 4; j++) {
        acc[j] += __shfl_xor(acc[j], 1);
        acc[j] += __shfl_xor(acc[j], 2);
        acc[j] += __shfl_xor(acc[j], 4);
    }
    if (r != 0) return;
    const u32* hbn = h2b + (size_t)n * 8;
    uint4 qn = *(const uint4*)hbn; uint2 pn = *(const uint2*)(hbn + 4);
    float hv[12] = { unlo(qn.x), unhi(qn.x), unlo(qn.y), unhi(qn.y),
                     unlo(qn.z), unhi(qn.z), unlo(qn.w), unhi(qn.w),
                     unlo(pn.x), unhi(pn.x), unlo(pn.y), unhi(pn.y) };
    float t4[4];
#pragma unroll
    for (int j = 0; j < 4; j++) {
        float v = acc[j] + b3[j];
#pragma unroll
        for (int i = 0; i < 12; i++) v += hv[i] * root3[i * 4 + j];
        t4[j] = v;
    }
    float m = fmaxf(fmaxf(t4[0], t4[1]), fmaxf(t4[2], t4[3]));
    float s = 0.0f;
#pragma unroll
    for (int j = 0; j < 4; j++) s += __expf(t4[j] - m);
    float lse = m + __logf(s);
    *(float4*)(out + (size_t)n * 4) =
        make_float4(t4[0] - lse, t4[1] - lse, t4[2] - lse, t4[3] - lse);
}

extern "C" void kernel_launch(void* const* d_in, const int* in_sizes, int n_in,
                              void* d_out, int out_size, void* d_ws, size_t ws_size,
                              hipStream_t stream) {
    const float* x     = (const float*)d_in[0];
    const int*   ei    = (const int*)d_in[1];   // [2, E]
    const int*   etype = (const int*)d_in[2];
    const float* w1    = (const float*)d_in[3];
    const float* root1 = (const float*)d_in[4];
    const float* b1    = (const float*)d_in[5];
    const float* w2    = (const float*)d_in[6];
    const float* root2 = (const float*)d_in[7];
    const float* b2    = (const float*)d_in[8];
    const float* w3    = (const float*)d_in[9];
    const float* root3 = (const float*)d_in[10];
    const float* b3    = (const float*)d_in[11];
    float* out = (float*)d_out;

    const int* src = ei;
    const int* dst = ei + NE;

    // workspace layout (bytes):
    //   ccursor : [NB]      u32   @ 0           (pad 1,600)
    //   off2    : [NN]      uint2 @ 1,600       (800,000 -> pad 801,664)
    //   tmp     : [NB*CAP]  u32   @ 801,664     (19,218,432 -> pad 20,020,224)
    //   recs    : [NB*CAP]  u32   @ 20,020,224  (19,218,432 -> ends 39,238,656)
    //   h1b     : [NN]      16B   @ 39,238,656  ( 1,600,000)
    //   h2b     : [NN]      32B   @ 40,838,656  ( 3,200,000)  -> total 44,038,656
    char* ws = (char*)d_ws;
    u32*   ccursor = (u32*)ws;
    uint2* off2    = (uint2*)(ws + 1600);
    u32*   tmp     = (u32*)(ws + 801664);
    u32*   recs    = (u32*)(ws + 20020224);
    uint4* h1b     = (uint4*)(ws + 39238656);
    u32*   h2b     = (u32*)(ws + 40838656);

    hipMemsetAsync(ccursor, 0, NB * sizeof(u32), stream);

    dim3 pgrid(NCHUNK);                      // 782
    dim3 ngrid(NB);                          // 391
    dim3 lgrid((NN * 8 + 255) / 256);        // 3125 (8 lanes/node)

    pass1_kernel<<<pgrid, 512, 0, stream>>>(src, dst, etype, ccursor, tmp);
    pass2_kernel<<<ngrid, 512, 0, stream>>>(tmp, ccursor, off2, recs, x, w1, root1, b1, h1b);
    layer2_kernel<<<lgrid, 256, 0, stream>>>(off2, recs, h1b, w2, root2, b2, h2b);
    layer3_kernel<<<lgrid, 256, 0, stream>>>(off2, recs, h2b, w3, root3, b3, out);
}

// Round 17
// 266.465 us; speedup vs baseline: 2.4825x; 1.0042x over previous
//
#include <hip/hip_runtime.h>
#include <math.h>

#define NN 100000
#define NE 3200000
#define NR 90
#define NB 391          // buckets of 256 nodes (dst>>8)
#define CH 4096         // edges per block in pass1
#define NCHUNK 782      // ceil(NE/CH)
#define CAP 12288       // padded per-bucket capacity (mean 8192, +45 sigma)

typedef unsigned int u32;
typedef unsigned short u16;

__device__ inline u32 pack2(float a, float b) {       // bf16(a) lo16, bf16(b) hi16 (RNE)
    u32 ua = __float_as_uint(a); ua += 0x7FFFu + ((ua >> 16) & 1u);
    u32 ub = __float_as_uint(b); ub += 0x7FFFu + ((ub >> 16) & 1u);
    return (ua >> 16) | (ub & 0xFFFF0000u);
}
__device__ inline float unlo(u32 w) { return __uint_as_float(w << 16); }
__device__ inline float unhi(u32 w) { return __uint_as_float(w & 0xFFFF0000u); }

// ---------------- pass 1: direct padded-bucket partition (no pre-count) ----------------
// tmp entry: (dst&255)<<24 | src<<7 | et ; bucket b's window is tmp[b*CAP ..]
__global__ __launch_bounds__(512) void pass1_kernel(const int* __restrict__ src,
                                                    const int* __restrict__ dst,
                                                    const int* __restrict__ et,
                                                    u32* __restrict__ ccursor,
                                                    u32* __restrict__ tmp) {
    __shared__ u32 cntA[NB];
    __shared__ u32 lcur[NB];
    __shared__ u32 delta[NB];
    __shared__ u32 scanS[512];
    __shared__ u32 lrecs[CH];
    __shared__ u16 lbid[CH];
    int tid = threadIdx.x;
    int c0 = blockIdx.x * CH;
    int c1 = c0 + CH; if (c1 > NE) c1 = NE;
    int nloc = c1 - c0;

    if (tid < NB) cntA[tid] = 0;
    __syncthreads();

    for (int e = c0 + tid; e < c1; e += 512)
        atomicAdd(&cntA[(u32)dst[e] >> 8], 1u);
    __syncthreads();

    scanS[tid] = (tid < NB) ? cntA[tid] : 0u;
    __syncthreads();
#pragma unroll
    for (int ofs = 1; ofs < 512; ofs <<= 1) {
        u32 v = (tid >= ofs) ? scanS[tid - ofs] : 0u;
        __syncthreads();
        scanS[tid] += v;
        __syncthreads();
    }
    if (tid < NB) {
        u32 excl = (tid == 0) ? 0u : scanS[tid - 1];
        lcur[tid] = excl;
        u32 c = cntA[tid];
        delta[tid] = c ? ((u32)tid * CAP + atomicAdd(&ccursor[tid], c) - excl) : 0u;
    }
    __syncthreads();

    for (int e = c0 + tid; e < c1; e += 512) {
        u32 d = (u32)dst[e];
        u32 b = d >> 8;
        u32 pos = atomicAdd(&lcur[b], 1u);
        lrecs[pos] = ((d & 255u) << 24) | ((u32)src[e] << 7) | (u32)et[e];
        lbid[pos] = (u16)b;
    }
    __syncthreads();

    for (int k = tid; k < nloc; k += 512)
        tmp[delta[lbid[k]] + k] = lrecs[k];
}

// ---------------- pass 2 + layer 1 fused (1024 threads/block) ----------------
// per-bucket fine sort -> off2=(start,end), recs(cnt<<24|src<<7|et);
// then layer1 (mean-aggr + root + bias + relu) for this bucket's 256 nodes.
__global__ __launch_bounds__(1024) void pass2_kernel(const u32* __restrict__ tmp,
                                                     const u32* __restrict__ ccursor,
                                                     uint2* __restrict__ off2,
                                                     u32* __restrict__ recs,
                                                     const float* __restrict__ x,
                                                     const float* __restrict__ w1,
                                                     const float* __restrict__ root1,
                                                     const float* __restrict__ b1,
                                                     uint4* __restrict__ h1b) {
    __shared__ u32 dh[256];          // per-node degree
    __shared__ u32 lc2[256];         // per-node cursor (relative)
    __shared__ u32 cnt32[256 * 23];  // per-(node,rel) u8 counts packed 4/word
    __shared__ u32 sh[256];          // inclusive scan (survives all phases)
    int tid = threadIdx.x;
    int b = blockIdx.x;
    u32 r0 = (u32)b * CAP;
    u32 r1 = r0 + ccursor[b];        // cursor's final value == bucket edge count

    if (tid < 256) dh[tid] = 0;
    for (int i = tid; i < 256 * 23; i += 1024) cnt32[i] = 0;
    __syncthreads();

    // A: per-node degrees
    for (u32 k = r0 + tid; k < r1; k += 1024)
        atomicAdd(&dh[tmp[k] >> 24], 1u);
    __syncthreads();

    // B: inclusive scan of dh (256 entries)
    if (tid < 256) sh[tid] = dh[tid];
    __syncthreads();
#pragma unroll
    for (int ofs = 1; ofs < 256; ofs <<= 1) {
        u32 v = (tid >= ofs && tid < 256) ? sh[tid - ofs] : 0u;
        __syncthreads();
        if (tid < 256) sh[tid] += v;
        __syncthreads();
    }
    int n = b * 256 + tid;
    if (tid < 256) {
        u32 excl = (tid == 0) ? 0u : sh[tid - 1];
        if (n < NN) off2[n] = make_uint2(r0 + excl, r0 + sh[tid]);
        lc2[tid] = excl;
    }
    __syncthreads();

    // C: fine scatter into this bucket's recs window + per-(node,rel) counts
    for (u32 k = r0 + tid; k < r1; k += 1024) {
        u32 v = tmp[k];
        u32 ln = v >> 24;
        u32 rec = v & 0xFFFFFFu;
        u32 rel = v & 127u;
        u32 pos = atomicAdd(&lc2[ln], 1u);
        recs[r0 + pos] = rec;
        atomicAdd(&cnt32[ln * 23 + (rel >> 2)], 1u << ((rel & 3u) * 8u));
    }
    __syncthreads();

    // D: embed per-(node,rel) count into top byte of each rec
    if (tid < 256 && n < NN) {
        u32 start = (tid == 0) ? 0u : sh[tid - 1];
        u32 end = sh[tid];
        for (u32 j = start; j < end; j++) {
            u32 rel = recs[r0 + j] & 127u;
            u32 c = (cnt32[tid * 23 + (rel >> 2)] >> ((rel & 3u) * 8u)) & 255u;
            recs[r0 + j] |= c << 24;
        }
    }
    __syncthreads();

    // E: layer 1 for this bucket's 256 nodes — 8 lanes/node, 2 sweeps of 128 nodes
#pragma unroll
    for (int g = 0; g < 2; g++) {
        int ln = g * 128 + (tid >> 3);         // 0..255
        int r = tid & 7;
        int nn = b * 256 + ln;
        float acc[8];
#pragma unroll
        for (int j = 0; j < 8; j++) acc[j] = 0.0f;
        if (nn < NN) {
            u32 k0 = r0 + ((ln == 0) ? 0u : sh[ln - 1]);
            u32 k1 = r0 + sh[ln];
            for (u32 k = k0 + r; k < k1; k += 8) {
                u32 rec = recs[k];
                u32 t = rec & 127u, s = (rec >> 7) & 0x1FFFFu;
                float norm = 1.0f / (float)(rec >> 24);
                float4 xv = *(const float4*)(x + (size_t)s * 4);
                float x0 = xv.x * norm, x1 = xv.y * norm;
                float x2 = xv.z * norm, x3 = xv.w * norm;
                const float* w = w1 + (size_t)t * 16;   // [2][2][4]
#pragma unroll
                for (int o = 0; o < 4; o++) {
                    acc[o]     += x0 * w[o]     + x1 * w[4 + o];
                    acc[4 + o] += x2 * w[8 + o] + x3 * w[12 + o];
                }
            }
        }
#pragma unroll
        for (int j = 0; j < 8; j++) {
            acc[j] += __shfl_xor(acc[j], 1);
            acc[j] += __shfl_xor(acc[j], 2);
            acc[j] += __shfl_xor(acc[j], 4);
        }
        if (r == 0 && nn < NN) {
            float4 xn = *(const float4*)(x + (size_t)nn * 4);
            float h[8];
#pragma unroll
            for (int j = 0; j < 8; j++) {
                float v = acc[j] + b1[j] + xn.x * root1[j] + xn.y * root1[8 + j]
                        + xn.z * root1[16 + j] + xn.w * root1[24 + j];
                h[j] = fmaxf(v, 0.0f);
            }
            h1b[nn] = make_uint4(pack2(h[0], h[1]), pack2(h[2], h[3]),
                                 pack2(h[4], h[5]), pack2(h[6], h[7]));
        }
    }
}

// ======== layers 2/3: 8 lanes/node, plain loads, bf16 tables (unchanged) ========

// ---------------- layer 2: add-aggr + root + bias + relu ----------------
__global__ __launch_bounds__(256) void layer2_kernel(
        const uint2* __restrict__ off2, const u32* __restrict__ recs,
        const uint4* __restrict__ h1b,
        const float* __restrict__ w2, const float* __restrict__ root2,
        const float* __restrict__ b2, u32* __restrict__ h2b) {
    int gid = blockIdx.x * 256 + threadIdx.x;
    int n = gid >> 3, r = gid & 7;
    if (n >= NN) return;
    float acc[12];
#pragma unroll
    for (int j = 0; j < 12; j++) acc[j] = 0.0f;

    uint2 o = off2[n];
    u32 k0 = o.x, k1 = o.y;
    for (u32 k = k0 + r; k < k1; k += 8) {
        u32 rec = recs[k];
        u32 t = rec & 127u, s = (rec >> 7) & 0x1FFFFu;
        uint4 hw = h1b[s];
        float a0 = unlo(hw.x), a1 = unhi(hw.x), a2 = unlo(hw.y), a3 = unhi(hw.y);
        float a4 = unlo(hw.z), a5 = unhi(hw.z), a6 = unlo(hw.w), a7 = unhi(hw.w);
        const float* w = w2 + (size_t)t * 24;   // [4][2][3]
#pragma unroll
        for (int o2 = 0; o2 < 3; o2++) {
            acc[o2]     += a0 * w[o2]      + a1 * w[3 + o2];
            acc[3 + o2] += a2 * w[6 + o2]  + a3 * w[9 + o2];
            acc[6 + o2] += a4 * w[12 + o2] + a5 * w[15 + o2];
            acc[9 + o2] += a6 * w[18 + o2] + a7 * w[21 + o2];
        }
    }
#pragma unroll
    for (int j = 0; j < 12; j++) {
        acc[j] += __shfl_xor(acc[j], 1);
        acc[j] += __shfl_xor(acc[j], 2);
        acc[j] += __shfl_xor(acc[j], 4);
    }
    if (r != 0) return;
    uint4 hn = h1b[n];
    float hv[8] = { unlo(hn.x), unhi(hn.x), unlo(hn.y), unhi(hn.y),
                    unlo(hn.z), unhi(hn.z), unlo(hn.w), unhi(hn.w) };
    float h[12];
#pragma unroll
    for (int j = 0; j < 12; j++) {
        float v = acc[j] + b2[j];
#pragma unroll
        for (int i = 0; i < 8; i++) v += hv[i] * root2[i * 12 + j];
        h[j] = fmaxf(v, 0.0f);
    }
    u32* hb = h2b + (size_t)n * 8;             // 32B stride, 24B used
    *(uint4*)hb = make_uint4(pack2(h[0], h[1]), pack2(h[2], h[3]),
                             pack2(h[4], h[5]), pack2(h[6], h[7]));
    *(uint2*)(hb + 4) = make_uint2(pack2(h[8], h[9]), pack2(h[10], h[11]));
}

// ---------------- layer 3: mean-aggr + root + bias + log_softmax ----------------
__global__ __launch_bounds__(256) void layer3_kernel(
        const uint2* __restrict__ off2, const u32* __restrict__ recs,
        const u32* __restrict__ h2b,
        const float* __restrict__ w3, const float* __restrict__ root3,
        const float* __restrict__ b3, float* __restrict__ out) {
    int gid = blockIdx.x * 256 + threadIdx.x;
    int n = gid >> 3, r = gid & 7;
    if (n >= NN) return;
    float acc[4] = {0.0f, 0.0f, 0.0f, 0.0f};
    uint2 o = off2[n];
    u32 k0 = o.x, k1 = o.y;
    for (u32 k = k0 + r; k < k1; k += 8) {
        u32 rec = recs[k];
        u32 t = rec & 127u, s = (rec >> 7) & 0x1FFFFu;
        float norm = 1.0f / (float)(rec >> 24);
        const u32* hb = h2b + (size_t)s * 8;
        uint4 q = *(const uint4*)hb;
        uint2 p = *(const uint2*)(hb + 4);
        float hsv[12] = { unlo(q.x), unhi(q.x), unlo(q.y), unhi(q.y),
                          unlo(q.z), unhi(q.z), unlo(q.w), unhi(q.w),
                          unlo(p.x), unhi(p.x), unlo(p.y), unhi(p.y) };
        const float* w = w3 + (size_t)t * 24;   // [2][6][2]
        float m0 = 0.0f, m1 = 0.0f, m2 = 0.0f, m3 = 0.0f;
#pragma unroll
        for (int i = 0; i < 6; i++) {
            m0 += hsv[i] * w[i * 2];          m1 += hsv[i] * w[i * 2 + 1];
            m2 += hsv[6 + i] * w[12 + i * 2]; m3 += hsv[6 + i] * w[12 + i * 2 + 1];
        }
        acc[0] += m0 * norm; acc[1] += m1 * norm;
        acc[2] += m2 * norm; acc[3] += m3 * norm;
    }
#pragma unroll
    for (int j = 0; j < 4; j++) {
        acc[j] += __shfl_xor(acc[j], 1);
        acc[j] += __shfl_xor(acc[j], 2);
        acc[j] += __shfl_xor(acc[j], 4);
    }
    if (r != 0) return;
    const u32* hbn = h2b + (size_t)n * 8;
    uint4 qn = *(const uint4*)hbn; uint2 pn = *(const uint2*)(hbn + 4);
    float hv[12] = { unlo(qn.x), unhi(qn.x), unlo(qn.y), unhi(qn.y),
                     unlo(qn.z), unhi(qn.z), unlo(qn.w), unhi(qn.w),
                     unlo(pn.x), unhi(pn.x), unlo(pn.y), unhi(pn.y) };
    float t4[4];
#pragma unroll
    for (int j = 0; j < 4; j++) {
        float v = acc[j] + b3[j];
#pragma unroll
        for (int i = 0; i < 12; i++) v += hv[i] * root3[i * 4 + j];
        t4[j] = v;
    }
    float m = fmaxf(fmaxf(t4[0], t4[1]), fmaxf(t4[2], t4[3]));
    float s = 0.0f;
#pragma unroll
    for (int j = 0; j < 4; j++) s += __expf(t4[j] - m);
    float lse = m + __logf(s);
    *(float4*)(out + (size_t)n * 4) =
        make_float4(t4[0] - lse, t4[1] - lse, t4[2] - lse, t4[3] - lse);
}

extern "C" void kernel_launch(void* const* d_in, const int* in_sizes, int n_in,
                              void* d_out, int out_size, void* d_ws, size_t ws_size,
                              hipStream_t stream) {
    const float* x     = (const float*)d_in[0];
    const int*   ei    = (const int*)d_in[1];   // [2, E]
    const int*   etype = (const int*)d_in[2];
    const float* w1    = (const float*)d_in[3];
    const float* root1 = (const float*)d_in[4];
    const float* b1    = (const float*)d_in[5];
    const float* w2    = (const float*)d_in[6];
    const float* root2 = (const float*)d_in[7];
    const float* b2    = (const float*)d_in[8];
    const float* w3    = (const float*)d_in[9];
    const float* root3 = (const float*)d_in[10];
    const float* b3    = (const float*)d_in[11];
    float* out = (float*)d_out;

    const int* src = ei;
    const int* dst = ei + NE;

    // workspace layout (bytes):
    //   ccursor : [NB]      u32   @ 0           (pad 1,600)
    //   off2    : [NN]      uint2 @ 1,600       (800,000 -> pad 801,664)
    //   tmp     : [NB*CAP]  u32   @ 801,664     (19,218,432 -> pad 20,020,224)
    //   recs    : [NB*CAP]  u32   @ 20,020,224  (19,218,432 -> ends 39,238,656)
    //   h1b     : [NN]      16B   @ 39,238,656  ( 1,600,000)
    //   h2b     : [NN]      32B   @ 40,838,656  ( 3,200,000)  -> total 44,038,656
    char* ws = (char*)d_ws;
    u32*   ccursor = (u32*)ws;
    uint2* off2    = (uint2*)(ws + 1600);
    u32*   tmp     = (u32*)(ws + 801664);
    u32*   recs    = (u32*)(ws + 20020224);
    uint4* h1b     = (uint4*)(ws + 39238656);
    u32*   h2b     = (u32*)(ws + 40838656);

    hipMemsetAsync(ccursor, 0, NB * sizeof(u32), stream);

    dim3 pgrid(NCHUNK);                      // 782
    dim3 ngrid(NB);                          // 391
    dim3 lgrid((NN * 8 + 255) / 256);        // 3125 (8 lanes/node)

    pass1_kernel<<<pgrid, 512, 0, stream>>>(src, dst, etype, ccursor, tmp);
    pass2_kernel<<<ngrid, 1024, 0, stream>>>(tmp, ccursor, off2, recs, x, w1, root1, b1, h1b);
    layer2_kernel<<<lgrid, 256, 0, stream>>>(off2, recs, h1b, w2, root2, b2, h2b);
    layer3_kernel<<<lgrid, 256, 0, stream>>>(off2, recs, h2b, w3, root3, b3, out);
}